// Round 1
// baseline (2362.872 us; speedup 1.0000x reference)
//
#include <hip/hip_runtime.h>
#include <cstdint>

using u64 = unsigned long long;

__device__ __forceinline__ unsigned sortable_f32(float f) {
  unsigned u = __float_as_uint(f);
  return (u & 0x80000000u) ? ~u : (u | 0x80000000u);
}

// ---------------- half-norms of target vectors: hn[b][n] = 0.5 * sum_c t^2 ----
__global__ __launch_bounds__(256) void hn_kernel(const float* __restrict__ tar,
                                                 float* __restrict__ hn,
                                                 int C, int N) {
  __shared__ float ps[256];
  int b = blockIdx.y;
  int nb = blockIdx.x * 32;
  int tn = threadIdx.x & 31, tg = threadIdx.x >> 5;  // 8 c-groups x 32 n
  const float* t = tar + (size_t)b * C * N + nb + tn;
  int cpg = C >> 3;
  int c0 = tg * cpg;
  float s = 0.f;
  for (int c = c0; c < c0 + cpg; ++c) {
    float v = t[(size_t)c * N];
    s = fmaf(v, v, s);
  }
  ps[threadIdx.x] = s;
  __syncthreads();
  if (threadIdx.x < 32) {
    float acc = 0.f;
#pragma unroll
    for (int g = 0; g < 8; ++g) acc += ps[g * 32 + threadIdx.x];  // fixed order: deterministic
    hn[(size_t)b * N + nb + threadIdx.x] = 0.5f * acc;
  }
}

// ---------------- fused GEMM + argmin -----------------------------------------
// score(m,n) = hn[n] - dot(src_m, tar_n); minimize over n  (== argmin d^2)
// key = sortable(score)<<32 | n  -> atomicMin gives min score, ties -> lowest n
template <int MI, int NJ, int BK>
__global__ __launch_bounds__(256, 2) void argmin_gemm(
    const float* __restrict__ src, const float* __restrict__ tar,
    const float* __restrict__ hn, u64* __restrict__ bestkey,
    int C, int M, int N, int nRange) {
  constexpr int BM = 16 * MI;
  constexpr int BN = 16 * NJ;
  __shared__ float As[BK * BM];
  __shared__ float Bs[BK * BN];
  const int tid = threadIdx.x;
  const int tx = tid & 15, ty = tid >> 4;
  const int mbase = blockIdx.x * BM;
  const int b = blockIdx.y;
  const int nbase0 = blockIdx.z * nRange;
  const float* srcB = src + (size_t)b * C * M;
  const float* tarB = tar + (size_t)b * C * N;
  const float* hnB = hn + (size_t)b * N;

  u64 bk[MI];
#pragma unroll
  for (int i = 0; i < MI; ++i) bk[i] = ~0ull;

  for (int nc = 0; nc < nRange; nc += BN) {
    const int nbase = nbase0 + nc;
    float acc[MI][NJ];
#pragma unroll
    for (int i = 0; i < MI; ++i)
#pragma unroll
      for (int j = 0; j < NJ; ++j) acc[i][j] = 0.f;

    for (int k0 = 0; k0 < C; k0 += BK) {
      const float* aG = srcB + (size_t)k0 * M + mbase;
      const float* bG = tarB + (size_t)k0 * N + nbase;
#pragma unroll
      for (int f = tid; f < BK * BM / 4; f += 256) {
        int r = f / (BM / 4), c4 = f % (BM / 4);
        ((float4*)As)[f] = *(const float4*)(aG + (size_t)r * M + c4 * 4);
      }
#pragma unroll
      for (int f = tid; f < BK * BN / 4; f += 256) {
        int r = f / (BN / 4), c4 = f % (BN / 4);
        ((float4*)Bs)[f] = *(const float4*)(bG + (size_t)r * N + c4 * 4);
      }
      __syncthreads();
#pragma unroll
      for (int kk = 0; kk < BK; ++kk) {
        float a[MI], bv[NJ];
#pragma unroll
        for (int i4 = 0; i4 < MI / 4; ++i4) {
          float4 v = ((const float4*)As)[(kk * BM + ty * MI) / 4 + i4];
          a[4 * i4 + 0] = v.x; a[4 * i4 + 1] = v.y;
          a[4 * i4 + 2] = v.z; a[4 * i4 + 3] = v.w;
        }
#pragma unroll
        for (int j4 = 0; j4 < NJ / 4; ++j4) {
          float4 v = ((const float4*)Bs)[(kk * BN + tx * NJ) / 4 + j4];
          bv[4 * j4 + 0] = v.x; bv[4 * j4 + 1] = v.y;
          bv[4 * j4 + 2] = v.z; bv[4 * j4 + 3] = v.w;
        }
#pragma unroll
        for (int i = 0; i < MI; ++i)
#pragma unroll
          for (int j = 0; j < NJ; ++j)
            acc[i][j] = fmaf(a[i], bv[j], acc[i][j]);
      }
      __syncthreads();
    }
    // fold this N-chunk into per-thread running best keys
#pragma unroll
    for (int j = 0; j < NJ; ++j) {
      int n = nbase + tx * NJ + j;
      float hv = hnB[n];
#pragma unroll
      for (int i = 0; i < MI; ++i) {
        float val = hv - acc[i][j];
        u64 key = ((u64)sortable_f32(val) << 32) | (unsigned)n;
        if (key < bk[i]) bk[i] = key;
      }
    }
  }
  // reduce across the 16 tx lanes sharing each row group, then one atomic/row
#pragma unroll
  for (int i = 0; i < MI; ++i) {
    u64 k = bk[i];
#pragma unroll
    for (int off = 8; off >= 1; off >>= 1) {
      unsigned lo = (unsigned)k, hi = (unsigned)(k >> 32);
      unsigned olo = __shfl_xor(lo, off, 16);
      unsigned ohi = __shfl_xor(hi, off, 16);
      u64 o = ((u64)ohi << 32) | olo;
      if (o < k) k = o;
    }
    if (tx == 0) {
      atomicMin(&bestkey[(size_t)b * M + mbase + ty * MI + i], k);
    }
  }
}

// ---------------- epilogue kernels --------------------------------------------
__global__ __launch_bounds__(256) void copy_src1(const float4* __restrict__ s,
                                                 float4* __restrict__ o) {
  size_t i = (size_t)blockIdx.x * 256 + threadIdx.x;  // 4 * 1024 * 1024 float4
  size_t b = i >> 20;
  size_t r = i & ((1u << 20) - 1);
  o[b * (size_t)(6144 * 1024) + r] = s[i];
}

__global__ __launch_bounds__(256) void gather_nn1(const float* __restrict__ tar,
                                                  const u64* __restrict__ bk,
                                                  float* __restrict__ out) {
  int b = blockIdx.y, c = blockIdx.x;  // c in [0,1024)
  const float* trow = tar + ((size_t)b * 1024 + c) * 4096;
  const u64* bkb = bk + (size_t)b * 4096;
  float* orow = out + ((size_t)b * 6144 + 1024 + c) * 4096;
  for (int p = threadIdx.x; p < 4096; p += 256) {
    int idx = (int)(unsigned)bkb[p];
    orow[p] = trow[idx];
  }
}

// bilinear x2 upsample (align_corners=False): even i: 0.25*in[k-1]+0.75*in[k];
// odd i: 0.75*in[k]+0.25*in[k+1]; edges clamp (== jax weight renormalization)
__global__ __launch_bounds__(256) void upsample2(const float* __restrict__ src2,
                                                 const float* __restrict__ tar2,
                                                 const u64* __restrict__ bk2,
                                                 float* __restrict__ out) {
  __shared__ float row[1024];
  int b = blockIdx.y, c = blockIdx.x;  // c in [0,4096)
  if (c < 2048) {
    const float* in = src2 + ((size_t)b * 2048 + c) * 1024;
    for (int p = threadIdx.x; p < 1024; p += 256) row[p] = in[p];
  } else {
    const float* trow = tar2 + ((size_t)b * 2048 + (c - 2048)) * 1024;
    const u64* bkb = bk2 + (size_t)b * 1024;
    for (int p = threadIdx.x; p < 1024; p += 256) {
      int idx = (int)(unsigned)bkb[p];
      row[p] = trow[idx];
    }
  }
  __syncthreads();
  float* orow = out + ((size_t)b * 6144 + 2048 + c) * 4096;
  for (int q = threadIdx.x; q < 4096; q += 256) {
    int y = q >> 6, x = q & 63;
    int ky = y >> 1, kx = x >> 1;
    int y0, y1, x0, x1;
    float wy0, wy1, wx0, wx1;
    if (y & 1) { y0 = ky; y1 = (ky + 1 < 32) ? ky + 1 : 31; wy0 = 0.75f; wy1 = 0.25f; }
    else       { y0 = (ky > 0) ? ky - 1 : 0; y1 = ky;       wy0 = 0.25f; wy1 = 0.75f; }
    if (x & 1) { x0 = kx; x1 = (kx + 1 < 32) ? kx + 1 : 31; wx0 = 0.75f; wx1 = 0.25f; }
    else       { x0 = (kx > 0) ? kx - 1 : 0; x1 = kx;       wx0 = 0.25f; wx1 = 0.75f; }
    float v = wy0 * (wx0 * row[y0 * 32 + x0] + wx1 * row[y0 * 32 + x1]) +
              wy1 * (wx0 * row[y1 * 32 + x0] + wx1 * row[y1 * 32 + x1]);
    orow[q] = v;
  }
}

// ---------------- launch ------------------------------------------------------
extern "C" void kernel_launch(void* const* d_in, const int* in_sizes, int n_in,
                              void* d_out, int out_size, void* d_ws, size_t ws_size,
                              hipStream_t stream) {
  const float* src1 = (const float*)d_in[0];  // [4,1024,64,64]
  const float* tar1 = (const float*)d_in[1];
  const float* src2 = (const float*)d_in[2];  // [4,2048,32,32]
  const float* tar2 = (const float*)d_in[3];
  float* out = (float*)d_out;                 // [4,6144,64,64]

  float* hn1 = (float*)d_ws;       // 4*4096 f32
  float* hn2 = hn1 + 4 * 4096;     // 4*1024 f32
  u64* bk1 = (u64*)(hn2 + 4 * 1024);  // 4*4096 u64
  u64* bk2 = bk1 + 4 * 4096;          // 4*1024 u64

  hipMemsetAsync(bk1, 0xFF, (size_t)(4 * 4096 + 4 * 1024) * sizeof(u64), stream);

  hn_kernel<<<dim3(4096 / 32, 4), 256, 0, stream>>>(tar1, hn1, 1024, 4096);
  hn_kernel<<<dim3(1024 / 32, 4), 256, 0, stream>>>(tar2, hn2, 2048, 1024);

  // level 1: M=N=4096, K=1024; BM=BN=128; N split 4 -> 512 blocks
  argmin_gemm<8, 8, 16><<<dim3(4096 / 128, 4, 4), 256, 0, stream>>>(
      src1, tar1, hn1, bk1, 1024, 4096, 4096, 1024);
  // level 2: M=N=1024, K=2048; BM=128, BN=64; N split 16 -> 512 blocks
  argmin_gemm<8, 4, 16><<<dim3(1024 / 128, 4, 16), 256, 0, stream>>>(
      src2, tar2, hn2, bk2, 2048, 1024, 1024, 64);

  copy_src1<<<16384, 256, 0, stream>>>((const float4*)src1, (float4*)out);
  gather_nn1<<<dim3(1024, 4), 256, 0, stream>>>(tar1, bk1, out);
  upsample2<<<dim3(4096, 4), 256, 0, stream>>>(src2, tar2, bk2, out);
}

// Round 2
// 887.011 us; speedup vs baseline: 2.6639x; 2.6639x over previous
//
#include <hip/hip_runtime.h>
#include <cstdint>

using u8 = unsigned char;
using u64 = unsigned long long;

typedef _Float16 f16x8 __attribute__((ext_vector_type(8)));
typedef float f32x4 __attribute__((ext_vector_type(4)));

__device__ __forceinline__ unsigned sortable_f32(float f) {
  unsigned u = __float_as_uint(f);
  return (u & 0x80000000u) ? ~u : (u | 0x80000000u);
}

__device__ __forceinline__ void gload16(const void* g, void* l) {
  __builtin_amdgcn_global_load_lds((const __attribute__((address_space(1))) void*)g,
                                   (__attribute__((address_space(3))) void*)l, 16, 0, 0);
}

// ---- convert fp32 [B][C][N] -> packed fp16 split [B][N][C/32][hi 64B | lo 64B]
__global__ __launch_bounds__(256) void split_convert(const float* __restrict__ in,
                                                     u8* __restrict__ out,
                                                     int C, int N) {
  const int n = blockIdx.y * 256 + threadIdx.x;
  const int c0 = blockIdx.x * 32;
  const int b = blockIdx.z;
  const float* inB = in + (size_t)b * C * N;
  f16x8 hv[4], lv[4];
#pragma unroll
  for (int g = 0; g < 4; ++g)
#pragma unroll
    for (int e = 0; e < 8; ++e) {
      float x = inB[(size_t)(c0 + g * 8 + e) * N + n];
      _Float16 h = (_Float16)x;
      float r = (x - (float)h) * 4096.f;  // exact split; scale dodges fp16 subnormals
      hv[g][e] = h;
      lv[g][e] = (_Float16)r;
    }
  const int Kc = C >> 5;
  u8* o = out + ((size_t)((size_t)b * N + n) * Kc + (c0 >> 5)) * 128;
#pragma unroll
  for (int g = 0; g < 4; ++g) {
    *(f16x8*)(o + g * 16) = hv[g];
    *(f16x8*)(o + 64 + g * 16) = lv[g];
  }
}

// ---- half-norms: hn[b][n] = 0.5 * sum_c t^2 (fp32, same scheme as round 1) --
__global__ __launch_bounds__(256) void hn_kernel(const float* __restrict__ tar,
                                                 float* __restrict__ hn,
                                                 int C, int N) {
  __shared__ float ps[256];
  int b = blockIdx.y;
  int nb = blockIdx.x * 32;
  int tn = threadIdx.x & 31, tg = threadIdx.x >> 5;
  const float* t = tar + (size_t)b * C * N + nb + tn;
  int cpg = C >> 3;
  int c0 = tg * cpg;
  float s = 0.f;
  for (int c = c0; c < c0 + cpg; ++c) {
    float v = t[(size_t)c * N];
    s = fmaf(v, v, s);
  }
  ps[threadIdx.x] = s;
  __syncthreads();
  if (threadIdx.x < 32) {
    float acc = 0.f;
#pragma unroll
    for (int g = 0; g < 8; ++g) acc += ps[g * 32 + threadIdx.x];
    hn[(size_t)b * N + nb + threadIdx.x] = 0.5f * acc;
  }
}

// ---- MFMA fp16-split GEMM + fused argmin ------------------------------------
// score(m,n) = hn[n] - dot(s_m, t_n); dot = hh + ll/4096 via 3 MFMA passes.
template <int MI, int NJ>
__global__ __launch_bounds__(256, 2) void nn_mfma(
    const u8* __restrict__ Ac, const u8* __restrict__ Bc,
    const float* __restrict__ hn, u64* __restrict__ bestkey,
    int M, int N, int Kc) {
  constexpr int BM = 32 * MI, BN = 32 * NJ;
  __shared__ u8 smem[(BM + BN) * 128];
  const int tid = threadIdx.x;
  const int lane = tid & 63;
  const int wid = tid >> 6;
  const int wrow = wid >> 1, wcol = wid & 1;
  const int lr = lane & 15, kh = lane >> 4;
  const int b = blockIdx.y;
  const int mbase = blockIdx.x * BM, nbase = blockIdx.z * BN;
  const size_t rstride = (size_t)Kc * 128;

  // staging: 1KB per wave-instr, 8 rows x 128B; source pre-swizzled chunk^=(row&7)
  const int trow = tid >> 3, tp = tid & 7;
  const int tswz = (tp ^ (trow & 7)) << 4;
  const u8* aCur = Ac + ((size_t)b * M + mbase + trow) * rstride + tswz;
  const u8* bCur = Bc + ((size_t)b * N + nbase + trow) * rstride + tswz;
  u8* l0 = smem + tid * 16;

  const int swz = (lr & 7) << 4;
  const int aoff = (wrow * MI * 16 + lr) * 128;
  const int boff = BM * 128 + (wcol * NJ * 16 + lr) * 128;
  const int hi_s = (kh << 4) ^ swz;
  const int lo_s = ((kh + 4) << 4) ^ swz;

  f32x4 hh[MI][NJ], ll[MI][NJ];
#pragma unroll
  for (int i = 0; i < MI; ++i)
#pragma unroll
    for (int j = 0; j < NJ; ++j) {
      hh[i][j] = f32x4{0.f, 0.f, 0.f, 0.f};
      ll[i][j] = f32x4{0.f, 0.f, 0.f, 0.f};
    }

  for (int kt = 0; kt < Kc; ++kt) {
#pragma unroll
    for (int v = 0; v < BM / 32; ++v)
      gload16(aCur + (size_t)v * 32 * rstride, l0 + v * 4096);
#pragma unroll
    for (int w = 0; w < BN / 32; ++w)
      gload16(bCur + (size_t)w * 32 * rstride, l0 + (BM / 32) * 4096 + w * 4096);
    aCur += 128;
    bCur += 128;
    __syncthreads();
    f16x8 ah[MI], al[MI], bh[NJ], bl[NJ];
#pragma unroll
    for (int i = 0; i < MI; ++i) {
      ah[i] = *(const f16x8*)(smem + aoff + i * 2048 + hi_s);
      al[i] = *(const f16x8*)(smem + aoff + i * 2048 + lo_s);
    }
#pragma unroll
    for (int j = 0; j < NJ; ++j) {
      bh[j] = *(const f16x8*)(smem + boff + j * 2048 + hi_s);
      bl[j] = *(const f16x8*)(smem + boff + j * 2048 + lo_s);
    }
#pragma unroll
    for (int i = 0; i < MI; ++i)
#pragma unroll
      for (int j = 0; j < NJ; ++j) {
        hh[i][j] = __builtin_amdgcn_mfma_f32_16x16x32_f16(ah[i], bh[j], hh[i][j], 0, 0, 0);
        ll[i][j] = __builtin_amdgcn_mfma_f32_16x16x32_f16(ah[i], bl[j], ll[i][j], 0, 0, 0);
        ll[i][j] = __builtin_amdgcn_mfma_f32_16x16x32_f16(al[i], bh[j], ll[i][j], 0, 0, 0);
      }
    __syncthreads();
  }

  // fused argmin: C/D layout col=lane&15, row=(lane>>4)*4+reg
  const float inv4096 = 2.44140625e-4f;
  const float* hnB = hn + (size_t)b * N;
  float hnv[NJ];
  int ncol[NJ];
#pragma unroll
  for (int j = 0; j < NJ; ++j) {
    ncol[j] = nbase + wcol * NJ * 16 + j * 16 + lr;
    hnv[j] = hnB[ncol[j]];
  }
#pragma unroll
  for (int i = 0; i < MI; ++i)
#pragma unroll
    for (int r = 0; r < 4; ++r) {
      u64 k = ~0ull;
#pragma unroll
      for (int j = 0; j < NJ; ++j) {
        float dot = hh[i][j][r] + ll[i][j][r] * inv4096;
        float val = hnv[j] - dot;
        u64 key = ((u64)sortable_f32(val) << 32) | (unsigned)ncol[j];
        if (key < k) k = key;
      }
#pragma unroll
      for (int off = 8; off >= 1; off >>= 1) {
        unsigned lo32 = (unsigned)k, hi32 = (unsigned)(k >> 32);
        unsigned olo = __shfl_xor(lo32, off);
        unsigned ohi = __shfl_xor(hi32, off);
        u64 o = ((u64)ohi << 32) | olo;
        if (o < k) k = o;
      }
      if (lr == 0)
        atomicMin(&bestkey[(size_t)b * M + mbase + wrow * MI * 16 + i * 16 + kh * 4 + r], k);
    }
}

// ---------------- epilogue kernels (unchanged from round 1) -------------------
__global__ __launch_bounds__(256) void copy_src1(const float4* __restrict__ s,
                                                 float4* __restrict__ o) {
  size_t i = (size_t)blockIdx.x * 256 + threadIdx.x;
  size_t b = i >> 20;
  size_t r = i & ((1u << 20) - 1);
  o[b * (size_t)(6144 * 1024) + r] = s[i];
}

__global__ __launch_bounds__(256) void gather_nn1(const float* __restrict__ tar,
                                                  const u64* __restrict__ bk,
                                                  float* __restrict__ out) {
  int b = blockIdx.y, c = blockIdx.x;
  const float* trow = tar + ((size_t)b * 1024 + c) * 4096;
  const u64* bkb = bk + (size_t)b * 4096;
  float* orow = out + ((size_t)b * 6144 + 1024 + c) * 4096;
  for (int p = threadIdx.x; p < 4096; p += 256) {
    int idx = (int)(unsigned)bkb[p];
    orow[p] = trow[idx];
  }
}

__global__ __launch_bounds__(256) void upsample2(const float* __restrict__ src2,
                                                 const float* __restrict__ tar2,
                                                 const u64* __restrict__ bk2,
                                                 float* __restrict__ out) {
  __shared__ float row[1024];
  int b = blockIdx.y, c = blockIdx.x;
  if (c < 2048) {
    const float* in = src2 + ((size_t)b * 2048 + c) * 1024;
    for (int p = threadIdx.x; p < 1024; p += 256) row[p] = in[p];
  } else {
    const float* trow = tar2 + ((size_t)b * 2048 + (c - 2048)) * 1024;
    const u64* bkb = bk2 + (size_t)b * 1024;
    for (int p = threadIdx.x; p < 1024; p += 256) {
      int idx = (int)(unsigned)bkb[p];
      row[p] = trow[idx];
    }
  }
  __syncthreads();
  float* orow = out + ((size_t)b * 6144 + 2048 + c) * 4096;
  for (int q = threadIdx.x; q < 4096; q += 256) {
    int y = q >> 6, x = q & 63;
    int ky = y >> 1, kx = x >> 1;
    int y0, y1, x0, x1;
    float wy0, wy1, wx0, wx1;
    if (y & 1) { y0 = ky; y1 = (ky + 1 < 32) ? ky + 1 : 31; wy0 = 0.75f; wy1 = 0.25f; }
    else       { y0 = (ky > 0) ? ky - 1 : 0; y1 = ky;       wy0 = 0.25f; wy1 = 0.75f; }
    if (x & 1) { x0 = kx; x1 = (kx + 1 < 32) ? kx + 1 : 31; wx0 = 0.75f; wx1 = 0.25f; }
    else       { x0 = (kx > 0) ? kx - 1 : 0; x1 = kx;       wx0 = 0.25f; wx1 = 0.75f; }
    float v = wy0 * (wx0 * row[y0 * 32 + x0] + wx1 * row[y0 * 32 + x1]) +
              wy1 * (wx0 * row[y1 * 32 + x0] + wx1 * row[y1 * 32 + x1]);
    orow[q] = v;
  }
}

// ---------------- launch ------------------------------------------------------
extern "C" void kernel_launch(void* const* d_in, const int* in_sizes, int n_in,
                              void* d_out, int out_size, void* d_ws, size_t ws_size,
                              hipStream_t stream) {
  const float* src1 = (const float*)d_in[0];  // [4,1024,64,64]
  const float* tar1 = (const float*)d_in[1];
  const float* src2 = (const float*)d_in[2];  // [4,2048,32,32]
  const float* tar2 = (const float*)d_in[3];
  float* out = (float*)d_out;                 // [4,6144,64,64] = 384 MiB

  // converted fp16-split tensors live in d_out's space as scratch (192 MiB),
  // fully overwritten by the epilogue afterwards.
  u8* scratch = (u8*)d_out;
  u8* c_src1 = scratch;                         // 64 MiB  [4,4096,32,128B]
  u8* c_tar1 = scratch + (64ull << 20);         // 64 MiB
  u8* c_src2 = scratch + (128ull << 20);        // 32 MiB  [4,1024,64,128B]
  u8* c_tar2 = scratch + (160ull << 20);        // 32 MiB

  float* hn1 = (float*)d_ws;          // 4*4096 f32
  float* hn2 = hn1 + 4 * 4096;        // 4*1024 f32
  u64* bk1 = (u64*)(hn2 + 4 * 1024);  // 4*4096 u64
  u64* bk2 = bk1 + 4 * 4096;          // 4*1024 u64

  split_convert<<<dim3(32, 16, 4), 256, 0, stream>>>(src1, c_src1, 1024, 4096);
  split_convert<<<dim3(32, 16, 4), 256, 0, stream>>>(tar1, c_tar1, 1024, 4096);
  split_convert<<<dim3(64, 4, 4), 256, 0, stream>>>(src2, c_src2, 2048, 1024);
  split_convert<<<dim3(64, 4, 4), 256, 0, stream>>>(tar2, c_tar2, 2048, 1024);

  hn_kernel<<<dim3(128, 4), 256, 0, stream>>>(tar1, hn1, 1024, 4096);
  hn_kernel<<<dim3(32, 4), 256, 0, stream>>>(tar2, hn2, 2048, 1024);
  hipMemsetAsync(bk1, 0xFF, (size_t)(4 * 4096 + 4 * 1024) * sizeof(u64), stream);

  // level 1: M=N=4096, K=1024 (Kc=32), tile 128x128
  nn_mfma<4, 4><<<dim3(32, 4, 32), 256, 0, stream>>>(c_src1, c_tar1, hn1, bk1, 4096, 4096, 32);
  // level 2: M=N=1024, K=2048 (Kc=64), tile 128x64
  nn_mfma<4, 2><<<dim3(8, 4, 16), 256, 0, stream>>>(c_src2, c_tar2, hn2, bk2, 1024, 1024, 64);

  copy_src1<<<16384, 256, 0, stream>>>((const float4*)src1, (float4*)out);
  gather_nn1<<<dim3(1024, 4), 256, 0, stream>>>(tar1, bk1, out);
  upsample2<<<dim3(4096, 4), 256, 0, stream>>>(src2, tar2, bk2, out);
}